// Round 5
// baseline (155.300 us; speedup 1.0000x reference)
//
#include <hip/hip_runtime.h>
#include <cstdint>
#include <cstddef>

// Problem constants: B=2, N=16384, K=32, F=64, E=16
#define LOGN 14

typedef __bf16 bf16x8 __attribute__((ext_vector_type(8)));
typedef float f32x4 __attribute__((ext_vector_type(4)));
typedef unsigned u32;

#define BARRIER() __builtin_amdgcn_s_barrier()
#define LGKM0()   __builtin_amdgcn_s_waitcnt(0xC07F)
#define SFENCE()  __builtin_amdgcn_sched_barrier(0)

__device__ __forceinline__ u32 fbits(float f) { return __builtin_bit_cast(u32, f); }
__device__ __forceinline__ u32 pkrne(float lo, float hi) {
  u32 a = fbits(lo); a = a + 0x7fffu + ((a >> 16) & 1u);
  u32 b = fbits(hi); b = b + 0x7fffu + ((b >> 16) & 1u);
  return (b & 0xffff0000u) | (a >> 16);
}

// k-enum (R9): ch = k>>3, wv = k&7: t = ch>>4, c = ch&15, L = 4c + (t>>1),
// n = 8(t&1) + wv. B-frag S for (lane c, tile lt) = S_row[4c+lt].

// wt[m][k] = w[L(k)][m][n(k)]/32 (bf16), 64x1024 = 128KB
__global__ void prep_wt(const float* __restrict__ w, unsigned short* __restrict__ wt) {
  int idx = blockIdx.x * 256 + threadIdx.x;
  int m = idx >> 10, k = idx & 1023;
  int ch = k >> 3, wv = k & 7, t = ch >> 4, cc = ch & 15;
  int l = (cc << 2) + (t >> 1), n = ((t & 1) << 3) + wv;
  u32 u = fbits(w[l * 1024 + m * 16 + n] * 0.03125f);
  wt[idx] = (unsigned short)((u + 0x7fffu + ((u >> 16) & 1u)) >> 16);
}

// nb[row][l] = bf16(nodes[row][l]) RNE (bit-identical to in-kernel conversion)
__global__ void prep_nb(const float* __restrict__ nodes, unsigned short* __restrict__ nb) {
  int idx = blockIdx.x * 256 + threadIdx.x;       // 262144 threads
  const float4* p = (const float4*)nodes + ((size_t)idx << 1);
  float4 a = p[0], b = p[1];
  uint4 o{pkrne(a.x, a.y), pkrne(a.z, a.w), pkrne(b.x, b.y), pkrne(b.z, b.w)};
  *((uint4*)nb + idx) = o;
}

__device__ __forceinline__ bf16x8 mk_bw(const float* wp) {
  float v[8];
  #pragma unroll
  for (int i = 0; i < 8; ++i) v[i] = wp[i] * 0.03125f;
  uint4 pk{pkrne(v[0], v[1]), pkrne(v[2], v[3]), pkrne(v[4], v[5]), pkrne(v[6], v[7])};
  return __builtin_bit_cast(bf16x8, pk);
}

// ============================================================================
// R11 FUSED kernel. History: R8 (WIN 68->59.6, sched_barrier pins); R9
// (NEUTRAL: 4x fewer VMEM instrs); R10 (NEUTRAL: -40% FETCH bytes, -VALU).
// Three nulls with dur pinned at 59us => binder is the PHASE STRUCTURE:
// A(gather, no compute) -> barrier -> B(MFMA) serializes per WG, and resident
// WGs move through phases in lockstep, so gather latency is never covered by
// compute. Fix: 4 tiles of 16 nodes per WG (grid 512), double-buffered g_lds
// (2x32KB), software pipeline: issue SE(t) gathers BEFORE phase B(t-1), pinned
// with sched_barrier(0); consume(t) after B(t-1) gets its vmcnt drained for
// free by B's own waits. One barrier per tile. SE-issue split in halves around
// B's midpoint to stay under the 63-outstanding vmcnt cap.
// ============================================================================
__global__ __launch_bounds__(256, 2)
void mp_fused(const int* __restrict__ nlist, const float* __restrict__ edges,
              const unsigned short* __restrict__ wt, const unsigned short* __restrict__ nb,
              float* __restrict__ out) {
  __shared__ u32 g_lds[2 * 16 * 512];   // 64 KB: double-buffered G

  const int tid = threadIdx.x;
  const int lane = tid & 63;
  const int wid = __builtin_amdgcn_readfirstlane(tid >> 6);
  const int q = lane >> 4, c = lane & 15;

  const int blk = blockIdx.x;                    // [0,512)
  const int xcd = blk & 7;
  const int batch = xcd >> 2;
  const int ordinal = ((blk >> 3) << 2) + (xcd & 3);   // [0,256)
  const int wg0 = (batch << LOGN) + (ordinal << 6);    // 64 nodes per WG
  const unsigned short* __restrict__ nbb = nb + ((size_t)batch << 20);

  const int nd0 = wid << 2;
  const int m = (wid << 4) + c;
  const unsigned short* __restrict__ wb = wt + ((size_t)m << 10) + (q << 3);

  int4  NI[4][2];      // neighbor indices, one tile (reused: read by SE, then overwritten by next nl)
  uint2 U[4][8];       // bf16 S rows, 4 nodes x 8 rows
  float E[4][8];       // edge features, 4 nodes x 8 rows

  auto issue_nl = [&](int g) {
    #pragma unroll
    for (int j = 0; j < 4; ++j) {
      const int* r = nlist + (((size_t)(g + nd0 + j)) << 5) + (q << 3);
      NI[j][0] = *(const int4*)r;
      NI[j][1] = *(const int4*)(r + 4);
    }
  };
  // gather S+E for nodes j0, j0+1 of tile with base g (32 loads)
  auto issue_se2 = [&](int g, int j0) {
    #pragma unroll
    for (int jj = 0; jj < 2; ++jj) {
      const int j = j0 + jj;
      const int ix[8] = {NI[j][0].x, NI[j][0].y, NI[j][0].z, NI[j][0].w,
                         NI[j][1].x, NI[j][1].y, NI[j][1].z, NI[j][1].w};
      #pragma unroll
      for (int i = 0; i < 8; ++i)
        U[j][i] = *(const uint2*)(nbb + ((size_t)(u32)ix[i] << 6) + (c << 2));
      const float* ep = edges + (((size_t)(g + nd0 + j)) << 9) + (q << 7) + c;
      #pragma unroll
      for (int i = 0; i < 8; ++i) E[j][i] = ep[i << 4];
    }
  };
  // pack + 16 MFMA + ds_write tile into buffer bsel
  auto consume_all = [&](int bsel) {
    #pragma unroll
    for (int j = 0; j < 4; ++j) {
      const int p = nd0 + j;
      uint4 apk{pkrne(E[j][0], E[j][1]), pkrne(E[j][2], E[j][3]),
                pkrne(E[j][4], E[j][5]), pkrne(E[j][6], E[j][7])};
      const bf16x8 af = __builtin_bit_cast(bf16x8, apk);
      #pragma unroll
      for (int lt = 0; lt < 4; ++lt) {
        const u32 sel = (lt & 1) ? 0x07060302u : 0x05040100u;
        u32 p0, p1, p2, p3;
        if (lt & 2) {
          p0 = __builtin_amdgcn_perm(U[j][1].y, U[j][0].y, sel);
          p1 = __builtin_amdgcn_perm(U[j][3].y, U[j][2].y, sel);
          p2 = __builtin_amdgcn_perm(U[j][5].y, U[j][4].y, sel);
          p3 = __builtin_amdgcn_perm(U[j][7].y, U[j][6].y, sel);
        } else {
          p0 = __builtin_amdgcn_perm(U[j][1].x, U[j][0].x, sel);
          p1 = __builtin_amdgcn_perm(U[j][3].x, U[j][2].x, sel);
          p2 = __builtin_amdgcn_perm(U[j][5].x, U[j][4].x, sel);
          p3 = __builtin_amdgcn_perm(U[j][7].x, U[j][6].x, sel);
        }
        uint4 spk{p0, p1, p2, p3};
        f32x4 acc{0.f, 0.f, 0.f, 0.f};
        acc = __builtin_amdgcn_mfma_f32_16x16x32_bf16(af,
                __builtin_bit_cast(bf16x8, spk), acc, 0, 0, 0);
        const u32 lo = pkrne(acc[0], acc[1]);
        const u32 hi = pkrne(acc[2], acc[3]);
        const int chunk = (c + (((lt << 1) + (q >> 1)) << 4)) ^ (p & 7);
        *(uint2*)&g_lds[(bsel << 13) + (p << 9) + (chunk << 2) + ((q & 1) << 1)] =
            uint2{lo, hi};
      }
    }
  };
  // half of phase B (16 K-steps), accumulating into ob
  auto phaseB_half = [&](int bsel, int s0, f32x4& ob) {
    #pragma unroll
    for (int s = s0; s < s0 + 16; ++s) {
      uint4 ar = *(const uint4*)&g_lds[(bsel << 13) + (c << 9) +
                                       ((((s << 2) + q) ^ (c & 7)) << 2)];
      ob = __builtin_amdgcn_mfma_f32_16x16x32_bf16(__builtin_bit_cast(bf16x8, ar),
                                                   *(const bf16x8*)(wb + (s << 5)),
                                                   ob, 0, 0, 0);
    }
  };
  auto store_out = [&](int g, const f32x4& ob) {
    #pragma unroll
    for (int r = 0; r < 4; ++r)
      out[((size_t)(g + (q << 2) + r) << 6) + m] = ob[r];
  };

  const int g0 = wg0, g1 = wg0 + 16, g2 = wg0 + 32, g3 = wg0 + 48;

  // ---- prologue: tile 0 gathered + consumed (serial, amortized 1/4) ----
  issue_nl(g0);
  issue_se2(g0, 0);
  issue_se2(g0, 2);
  issue_nl(g1);
  consume_all(0);                 // -> buf0
  LGKM0(); BARRIER();

  f32x4 ob;

  // ---- tile 1 block: B(0) with SE(1) in flight ----
  issue_se2(g1, 0);
  SFENCE();
  ob = f32x4{0.f, 0.f, 0.f, 0.f};
  phaseB_half(0, 0, ob);
  issue_se2(g1, 2);
  issue_nl(g2);
  SFENCE();
  phaseB_half(0, 16, ob);
  store_out(g0, ob);
  consume_all(1);                 // -> buf1 (B's own vmcnt waits drained SE(1))
  LGKM0(); BARRIER();

  // ---- tile 2 block: B(1) with SE(2) in flight ----
  issue_se2(g2, 0);
  SFENCE();
  ob = f32x4{0.f, 0.f, 0.f, 0.f};
  phaseB_half(1, 0, ob);
  issue_se2(g2, 2);
  issue_nl(g3);
  SFENCE();
  phaseB_half(1, 16, ob);
  store_out(g1, ob);
  consume_all(0);                 // -> buf0
  LGKM0(); BARRIER();

  // ---- tile 3 block: B(2) with SE(3) in flight ----
  issue_se2(g3, 0);
  SFENCE();
  ob = f32x4{0.f, 0.f, 0.f, 0.f};
  phaseB_half(0, 0, ob);
  issue_se2(g3, 2);
  SFENCE();
  phaseB_half(0, 16, ob);
  store_out(g2, ob);
  consume_all(1);                 // -> buf1
  LGKM0(); BARRIER();

  // ---- epilogue: B(3) ----
  ob = f32x4{0.f, 0.f, 0.f, 0.f};
  phaseB_half(1, 0, ob);
  phaseB_half(1, 16, ob);
  store_out(g3, ob);
}

// ============================================================================
// Fallback (no/partial workspace): R4's unfused kernel, grid 2048.
// ============================================================================
template <int MODE>
__global__ __launch_bounds__(256, 3)
void mp_kernel(const float* __restrict__ nodes, const int* __restrict__ nlist,
               const float* __restrict__ edges, const unsigned short* __restrict__ wt,
               const float* __restrict__ w, float* __restrict__ out) {
  __shared__ u32 g_lds[16 * 512];

  const int tid = threadIdx.x;
  const int lane = tid & 63;
  const int wid = __builtin_amdgcn_readfirstlane(tid >> 6);
  const int q = lane >> 4, c = lane & 15;

  const int blk = blockIdx.x;
  const int xcd = blk & 7;
  const int batch = xcd >> 2;
  const int ordinal = ((blk >> 3) << 2) + (xcd & 3);
  const int wg0 = (batch << LOGN) + (ordinal << 4);
  const float* __restrict__ nbase = nodes + ((size_t)batch << 20);

  const int nd0 = wid << 2;

  auto issue_nl = [&](int t, int4* ni) {
    const int* r = nlist + (((size_t)(wg0 + nd0 + t)) << 5) + (q << 3);
    ni[0] = *(const int4*)r;
    ni[1] = *(const int4*)(r + 4);
  };
  auto issue_se = [&](int t, const int4* ni, f32x4* R, float* Ee) {
    const int ix[8] = {ni[0].x, ni[0].y, ni[0].z, ni[0].w,
                       ni[1].x, ni[1].y, ni[1].z, ni[1].w};
    #pragma unroll
    for (int i = 0; i < 8; ++i)
      R[i] = *(const f32x4*)(nbase + ((size_t)(u32)ix[i] << 6) + (c << 2));
    const float* ep = edges + (((size_t)(wg0 + nd0 + t)) << 9) + (q << 7) + c;
    #pragma unroll
    for (int i = 0; i < 8; ++i) Ee[i] = ep[i << 4];
  };
  auto consume = [&](int p, const f32x4* R, const float* Ee) {
    uint4 apk{pkrne(Ee[0], Ee[1]), pkrne(Ee[2], Ee[3]),
              pkrne(Ee[4], Ee[5]), pkrne(Ee[6], Ee[7])};
    const bf16x8 af = __builtin_bit_cast(bf16x8, apk);
    #pragma unroll
    for (int lt = 0; lt < 4; ++lt) {
      uint4 spk{pkrne(R[0][lt], R[1][lt]), pkrne(R[2][lt], R[3][lt]),
                pkrne(R[4][lt], R[5][lt]), pkrne(R[6][lt], R[7][lt])};
      f32x4 acc{0.f, 0.f, 0.f, 0.f};
      acc = __builtin_amdgcn_mfma_f32_16x16x32_bf16(af,
              __builtin_bit_cast(bf16x8, spk), acc, 0, 0, 0);
      const u32 lo = pkrne(acc[0], acc[1]);
      const u32 hi = pkrne(acc[2], acc[3]);
      const int chunk = (c + (((lt << 1) + (q >> 1)) << 4)) ^ (p & 7);
      *(uint2*)&g_lds[(p << 9) + (chunk << 2) + ((q & 1) << 1)] = uint2{lo, hi};
    }
  };

  {
    int4 ni0[2], ni1[2];
    f32x4 R0[8], R1[8];
    float E0[8], E1[8];
    issue_nl(0, ni0);
    issue_nl(1, ni1);
    issue_se(0, ni0, R0, E0);
    issue_nl(2, ni0);
    issue_se(1, ni1, R1, E1);
    issue_nl(3, ni1);
    SFENCE();
    consume(nd0 + 0, R0, E0);
    issue_se(2, ni0, R0, E0);
    SFENCE();
    consume(nd0 + 1, R1, E1);
    issue_se(3, ni1, R1, E1);
    SFENCE();
    consume(nd0 + 2, R0, E0);
    consume(nd0 + 3, R1, E1);
  }

  LGKM0();
  BARRIER();

  const int m = (wid << 4) + c;
  f32x4 ob{0.f, 0.f, 0.f, 0.f};
  if constexpr (MODE >= 1) {
    const unsigned short* wb = wt + ((size_t)m << 10) + (q << 3);
    #pragma unroll 8
    for (int s = 0; s < 32; ++s) {
      uint4 ar = *(const uint4*)&g_lds[(c << 9) + ((((s << 2) + q) ^ (c & 7)) << 2)];
      ob = __builtin_amdgcn_mfma_f32_16x16x32_bf16(__builtin_bit_cast(bf16x8, ar),
                                                   *(const bf16x8*)(wb + (s << 5)),
                                                   ob, 0, 0, 0);
    }
  } else {
    #pragma unroll 4
    for (int s = 0; s < 32; ++s) {
      uint4 ar = *(const uint4*)&g_lds[(c << 9) + ((((s << 2) + q) ^ (c & 7)) << 2)];
      const int ch = (s << 2) + q;
      const int l = ((ch & 15) << 2) + (ch >> 5);
      const int n0 = ((ch >> 4) & 1) << 3;
      const float* wp = w + l * 1024 + m * 16 + n0;
      ob = __builtin_amdgcn_mfma_f32_16x16x32_bf16(__builtin_bit_cast(bf16x8, ar),
                                                   mk_bw(wp), ob, 0, 0, 0);
    }
  }

  #pragma unroll
  for (int r = 0; r < 4; ++r)
    out[((size_t)(wg0 + (q << 2) + r) << 6) + m] = ob[r];
}

extern "C" void kernel_launch(void* const* d_in, const int* in_sizes, int n_in,
                              void* d_out, int out_size, void* d_ws, size_t ws_size,
                              hipStream_t stream) {
  const float* nodes = (const float*)d_in[0];
  const int*   nlist = (const int*)d_in[1];
  const float* edges = (const float*)d_in[2];
  const float* w     = (const float*)d_in[3];
  float* out = (float*)d_out;

  const size_t WT_BYTES = 131072;               // 64x1024 bf16
  const size_t NB_BYTES = (size_t)1 << 22;      // 2x16384x64 bf16 = 4 MB

  if (ws_size >= WT_BYTES + NB_BYTES) {
    unsigned short* wt = (unsigned short*)d_ws;
    unsigned short* nb = wt + 65536;
    prep_wt<<<256, 256, 0, stream>>>(w, wt);
    prep_nb<<<1024, 256, 0, stream>>>(nodes, nb);
    mp_fused<<<512, 256, 0, stream>>>(nlist, edges, wt, nb, out);
  } else if (ws_size >= WT_BYTES) {
    unsigned short* wt = (unsigned short*)d_ws;
    prep_wt<<<256, 256, 0, stream>>>(w, wt);
    mp_kernel<1><<<2048, 256, 0, stream>>>(nodes, nlist, edges, wt, w, out);
  } else {
    mp_kernel<0><<<2048, 256, 0, stream>>>(nodes, nlist, edges, nullptr, w, out);
  }
}

// Round 6
// 135.540 us; speedup vs baseline: 1.1458x; 1.1458x over previous
//
#include <hip/hip_runtime.h>
#include <cstdint>
#include <cstddef>

// Problem constants: B=2, N=16384, K=32, F=64, E=16
#define LOGN 14

typedef __bf16 bf16x8 __attribute__((ext_vector_type(8)));
typedef float f32x4 __attribute__((ext_vector_type(4)));
typedef unsigned u32;

#define BARRIER() __builtin_amdgcn_s_barrier()
#define LGKM0()   __builtin_amdgcn_s_waitcnt(0xC07F)
#define SFENCE()  __builtin_amdgcn_sched_barrier(0)

__device__ __forceinline__ u32 fbits(float f) { return __builtin_bit_cast(u32, f); }
__device__ __forceinline__ u32 pkrne(float lo, float hi) {
  u32 a = fbits(lo); a = a + 0x7fffu + ((a >> 16) & 1u);
  u32 b = fbits(hi); b = b + 0x7fffu + ((b >> 16) & 1u);
  return (b & 0xffff0000u) | (a >> 16);
}

// k-enum (R9): ch = k>>3, wv = k&7: t = ch>>4, c = ch&15, L = 4c + (t>>1),
// n = 8(t&1) + wv. B-frag S for (lane c, tile lt) = S_row[4c+lt].

// wt[m][k] = w[L(k)][m][n(k)]/32 (bf16), 64x1024 = 128KB
__global__ void prep_wt(const float* __restrict__ w, unsigned short* __restrict__ wt) {
  int idx = blockIdx.x * 256 + threadIdx.x;
  int m = idx >> 10, k = idx & 1023;
  int ch = k >> 3, wv = k & 7, t = ch >> 4, cc = ch & 15;
  int l = (cc << 2) + (t >> 1), n = ((t & 1) << 3) + wv;
  u32 u = fbits(w[l * 1024 + m * 16 + n] * 0.03125f);
  wt[idx] = (unsigned short)((u + 0x7fffu + ((u >> 16) & 1u)) >> 16);
}

// nb[row][l] = bf16(nodes[row][l]) RNE (bit-identical to in-kernel conversion)
__global__ void prep_nb(const float* __restrict__ nodes, unsigned short* __restrict__ nb) {
  int idx = blockIdx.x * 256 + threadIdx.x;       // 262144 threads
  const float4* p = (const float4*)nodes + ((size_t)idx << 1);
  float4 a = p[0], b = p[1];
  uint4 o{pkrne(a.x, a.y), pkrne(a.z, a.w), pkrne(b.x, b.y), pkrne(b.z, b.w)};
  *((uint4*)nb + idx) = o;
}

__device__ __forceinline__ bf16x8 mk_bw(const float* wp) {
  float v[8];
  #pragma unroll
  for (int i = 0; i < 8; ++i) v[i] = wp[i] * 0.03125f;
  uint4 pk{pkrne(v[0], v[1]), pkrne(v[2], v[3]), pkrne(v[4], v[5]), pkrne(v[6], v[7])};
  return __builtin_bit_cast(bf16x8, pk);
}

// ============================================================================
// R12 (this round). Findings so far: dur pinned ~59us across R2(fences)/
// R3(4x fewer instrs)/R4(-40% FETCH, -50% S lines). The invariant that fits
// all rounds: per-CU outstanding-miss concurrency cap (~40 lines, Little's
// law on 1.4 TB/s @ 300-900cy). Time ~ sum(lines x latency)/C. Dominant
// terms: wt re-reads (16K lines/CU x 250cy -- each wave re-streams its 32KB
// wt slice from L2 EVERY round, L1-thrashed) and edges (4K x 900cy HBM).
// R5 (fused, FAILED 65.7): right structure, but (256,2) reg-cap forced
// scratch spills (WRITE +5.6MB).
// Fix: R5's fused 4-tile skeleton + wt held in 128 VGPRs loaded ONCE at
// kernel entry (phase B = pure LDS+MFMA, zero VMEM), __launch_bounds__(256,1)
// so ~320 VGPRs allocate WITHOUT spill (the R1/R5 killer). 4 waves/CU by
// design: TLP is not the binding resource, the miss-concurrency cap is.
// wt lines/CU: 16K -> 4K (once per WG-visit, 2 visits).
// ============================================================================
__global__ __launch_bounds__(256, 1)
void mp_fused(const int* __restrict__ nlist, const float* __restrict__ edges,
              const unsigned short* __restrict__ wt, const unsigned short* __restrict__ nb,
              float* __restrict__ out) {
  __shared__ u32 g_lds[2 * 16 * 512];   // 64 KB: double-buffered G

  const int tid = threadIdx.x;
  const int lane = tid & 63;
  const int wid = __builtin_amdgcn_readfirstlane(tid >> 6);
  const int q = lane >> 4, c = lane & 15;

  const int blk = blockIdx.x;                    // [0,512)
  const int xcd = blk & 7;
  const int batch = xcd >> 2;
  const int ordinal = ((blk >> 3) << 2) + (xcd & 3);   // [0,256)
  const int wg0 = (batch << LOGN) + (ordinal << 6);    // 64 nodes per WG
  const unsigned short* __restrict__ nbb = nb + ((size_t)batch << 20);

  const int nd0 = wid << 2;
  const int m = (wid << 4) + c;

  // ---- wt slice -> 128 VGPRs, issued FIRST (oldest in vmcnt queue; L2-hit;
  // guaranteed complete before first use by prologue's own vmcnt waits) ----
  bf16x8 wtreg[32];
  {
    const unsigned short* wb = wt + ((size_t)m << 10) + (q << 3);
    #pragma unroll
    for (int s = 0; s < 32; ++s) wtreg[s] = *(const bf16x8*)(wb + (s << 5));
  }

  int4  NI[4][2];      // neighbor indices for one tile
  uint2 U[4][8];       // bf16 S rows, 4 nodes x 8 rows
  float E[4][8];       // edge features, 4 nodes x 8 rows

  auto issue_nl = [&](int g) {
    #pragma unroll
    for (int j = 0; j < 4; ++j) {
      const int* r = nlist + (((size_t)(g + nd0 + j)) << 5) + (q << 3);
      NI[j][0] = *(const int4*)r;
      NI[j][1] = *(const int4*)(r + 4);
    }
  };
  // gather S+E for nodes j0, j0+1 of tile with base g (32 loads)
  auto issue_se2 = [&](int g, int j0) {
    #pragma unroll
    for (int jj = 0; jj < 2; ++jj) {
      const int j = j0 + jj;
      const int ix[8] = {NI[j][0].x, NI[j][0].y, NI[j][0].z, NI[j][0].w,
                         NI[j][1].x, NI[j][1].y, NI[j][1].z, NI[j][1].w};
      #pragma unroll
      for (int i = 0; i < 8; ++i)
        U[j][i] = *(const uint2*)(nbb + ((size_t)(u32)ix[i] << 6) + (c << 2));
      const float* ep = edges + (((size_t)(g + nd0 + j)) << 9) + (q << 7) + c;
      #pragma unroll
      for (int i = 0; i < 8; ++i) E[j][i] = ep[i << 4];
    }
  };
  // pack + 16 MFMA + ds_write tile into buffer bsel
  auto consume_all = [&](int bsel) {
    #pragma unroll
    for (int j = 0; j < 4; ++j) {
      const int p = nd0 + j;
      uint4 apk{pkrne(E[j][0], E[j][1]), pkrne(E[j][2], E[j][3]),
                pkrne(E[j][4], E[j][5]), pkrne(E[j][6], E[j][7])};
      const bf16x8 af = __builtin_bit_cast(bf16x8, apk);
      #pragma unroll
      for (int lt = 0; lt < 4; ++lt) {
        const u32 sel = (lt & 1) ? 0x07060302u : 0x05040100u;
        u32 p0, p1, p2, p3;
        if (lt & 2) {
          p0 = __builtin_amdgcn_perm(U[j][1].y, U[j][0].y, sel);
          p1 = __builtin_amdgcn_perm(U[j][3].y, U[j][2].y, sel);
          p2 = __builtin_amdgcn_perm(U[j][5].y, U[j][4].y, sel);
          p3 = __builtin_amdgcn_perm(U[j][7].y, U[j][6].y, sel);
        } else {
          p0 = __builtin_amdgcn_perm(U[j][1].x, U[j][0].x, sel);
          p1 = __builtin_amdgcn_perm(U[j][3].x, U[j][2].x, sel);
          p2 = __builtin_amdgcn_perm(U[j][5].x, U[j][4].x, sel);
          p3 = __builtin_amdgcn_perm(U[j][7].x, U[j][6].x, sel);
        }
        uint4 spk{p0, p1, p2, p3};
        f32x4 acc{0.f, 0.f, 0.f, 0.f};
        acc = __builtin_amdgcn_mfma_f32_16x16x32_bf16(af,
                __builtin_bit_cast(bf16x8, spk), acc, 0, 0, 0);
        const u32 lo = pkrne(acc[0], acc[1]);
        const u32 hi = pkrne(acc[2], acc[3]);
        const int chunk = (c + (((lt << 1) + (q >> 1)) << 4)) ^ (p & 7);
        *(uint2*)&g_lds[(bsel << 13) + (p << 9) + (chunk << 2) + ((q & 1) << 1)] =
            uint2{lo, hi};
      }
    }
  };
  auto store_out = [&](int g, const f32x4& ob) {
    #pragma unroll
    for (int r = 0; r < 4; ++r)
      out[((size_t)(g + (q << 2) + r) << 6) + m] = ob[r];
  };

  // ---- prologue: tile 0 gathered + consumed ----
  issue_nl(wg0);
  issue_se2(wg0, 0);
  issue_se2(wg0, 2);
  issue_nl(wg0 + 16);
  consume_all(0);                 // -> buf0 (its vmcnt waits also drain wtreg)
  LGKM0(); BARRIER();

  // ---- main loop: B(t) from buf(t&1), SE(t+1) in flight, consume -> buf(t&1)^1
  #pragma unroll
  for (int t = 0; t < 3; ++t) {
    const int gn = wg0 + ((t + 1) << 4);
    issue_se2(gn, 0);
    SFENCE();
    f32x4 ob{0.f, 0.f, 0.f, 0.f};
    #pragma unroll
    for (int s = 0; s < 16; ++s) {
      uint4 ar = *(const uint4*)&g_lds[((t & 1) << 13) + (c << 9) +
                                       ((((s << 2) + q) ^ (c & 7)) << 2)];
      ob = __builtin_amdgcn_mfma_f32_16x16x32_bf16(__builtin_bit_cast(bf16x8, ar),
                                                   wtreg[s], ob, 0, 0, 0);
    }
    issue_se2(gn, 2);
    if (t < 2) issue_nl(wg0 + ((t + 2) << 4));
    SFENCE();
    #pragma unroll
    for (int s = 16; s < 32; ++s) {
      uint4 ar = *(const uint4*)&g_lds[((t & 1) << 13) + (c << 9) +
                                       ((((s << 2) + q) ^ (c & 7)) << 2)];
      ob = __builtin_amdgcn_mfma_f32_16x16x32_bf16(__builtin_bit_cast(bf16x8, ar),
                                                   wtreg[s], ob, 0, 0, 0);
    }
    store_out(wg0 + (t << 4), ob);
    consume_all((t & 1) ^ 1);
    LGKM0(); BARRIER();
  }

  // ---- epilogue: B(3) from buf1 ----
  {
    f32x4 ob{0.f, 0.f, 0.f, 0.f};
    #pragma unroll
    for (int s = 0; s < 32; ++s) {
      uint4 ar = *(const uint4*)&g_lds[(1 << 13) + (c << 9) +
                                       ((((s << 2) + q) ^ (c & 7)) << 2)];
      ob = __builtin_amdgcn_mfma_f32_16x16x32_bf16(__builtin_bit_cast(bf16x8, ar),
                                                   wtreg[s], ob, 0, 0, 0);
    }
    store_out(wg0 + 48, ob);
  }
}

// ============================================================================
// Fallback (no/partial workspace): R4's unfused kernel, grid 2048.
// ============================================================================
template <int MODE>
__global__ __launch_bounds__(256, 3)
void mp_kernel(const float* __restrict__ nodes, const int* __restrict__ nlist,
               const float* __restrict__ edges, const unsigned short* __restrict__ wt,
               const float* __restrict__ w, float* __restrict__ out) {
  __shared__ u32 g_lds[16 * 512];

  const int tid = threadIdx.x;
  const int lane = tid & 63;
  const int wid = __builtin_amdgcn_readfirstlane(tid >> 6);
  const int q = lane >> 4, c = lane & 15;

  const int blk = blockIdx.x;
  const int xcd = blk & 7;
  const int batch = xcd >> 2;
  const int ordinal = ((blk >> 3) << 2) + (xcd & 3);
  const int wg0 = (batch << LOGN) + (ordinal << 4);
  const float* __restrict__ nbase = nodes + ((size_t)batch << 20);

  const int nd0 = wid << 2;

  auto issue_nl = [&](int t, int4* ni) {
    const int* r = nlist + (((size_t)(wg0 + nd0 + t)) << 5) + (q << 3);
    ni[0] = *(const int4*)r;
    ni[1] = *(const int4*)(r + 4);
  };
  auto issue_se = [&](int t, const int4* ni, f32x4* R, float* Ee) {
    const int ix[8] = {ni[0].x, ni[0].y, ni[0].z, ni[0].w,
                       ni[1].x, ni[1].y, ni[1].z, ni[1].w};
    #pragma unroll
    for (int i = 0; i < 8; ++i)
      R[i] = *(const f32x4*)(nbase + ((size_t)(u32)ix[i] << 6) + (c << 2));
    const float* ep = edges + (((size_t)(wg0 + nd0 + t)) << 9) + (q << 7) + c;
    #pragma unroll
    for (int i = 0; i < 8; ++i) Ee[i] = ep[i << 4];
  };
  auto consume = [&](int p, const f32x4* R, const float* Ee) {
    uint4 apk{pkrne(Ee[0], Ee[1]), pkrne(Ee[2], Ee[3]),
              pkrne(Ee[4], Ee[5]), pkrne(Ee[6], Ee[7])};
    const bf16x8 af = __builtin_bit_cast(bf16x8, apk);
    #pragma unroll
    for (int lt = 0; lt < 4; ++lt) {
      uint4 spk{pkrne(R[0][lt], R[1][lt]), pkrne(R[2][lt], R[3][lt]),
                pkrne(R[4][lt], R[5][lt]), pkrne(R[6][lt], R[7][lt])};
      f32x4 acc{0.f, 0.f, 0.f, 0.f};
      acc = __builtin_amdgcn_mfma_f32_16x16x32_bf16(af,
              __builtin_bit_cast(bf16x8, spk), acc, 0, 0, 0);
      const u32 lo = pkrne(acc[0], acc[1]);
      const u32 hi = pkrne(acc[2], acc[3]);
      const int chunk = (c + (((lt << 1) + (q >> 1)) << 4)) ^ (p & 7);
      *(uint2*)&g_lds[(p << 9) + (chunk << 2) + ((q & 1) << 1)] = uint2{lo, hi};
    }
  };

  {
    int4 ni0[2], ni1[2];
    f32x4 R0[8], R1[8];
    float E0[8], E1[8];
    issue_nl(0, ni0);
    issue_nl(1, ni1);
    issue_se(0, ni0, R0, E0);
    issue_nl(2, ni0);
    issue_se(1, ni1, R1, E1);
    issue_nl(3, ni1);
    SFENCE();
    consume(nd0 + 0, R0, E0);
    issue_se(2, ni0, R0, E0);
    SFENCE();
    consume(nd0 + 1, R1, E1);
    issue_se(3, ni1, R1, E1);
    SFENCE();
    consume(nd0 + 2, R0, E0);
    consume(nd0 + 3, R1, E1);
  }

  LGKM0();
  BARRIER();

  const int m = (wid << 4) + c;
  f32x4 ob{0.f, 0.f, 0.f, 0.f};
  if constexpr (MODE >= 1) {
    const unsigned short* wb = wt + ((size_t)m << 10) + (q << 3);
    #pragma unroll 8
    for (int s = 0; s < 32; ++s) {
      uint4 ar = *(const uint4*)&g_lds[(c << 9) + ((((s << 2) + q) ^ (c & 7)) << 2)];
      ob = __builtin_amdgcn_mfma_f32_16x16x32_bf16(__builtin_bit_cast(bf16x8, ar),
                                                   *(const bf16x8*)(wb + (s << 5)),
                                                   ob, 0, 0, 0);
    }
  } else {
    #pragma unroll 4
    for (int s = 0; s < 32; ++s) {
      uint4 ar = *(const uint4*)&g_lds[(c << 9) + ((((s << 2) + q) ^ (c & 7)) << 2)];
      const int ch = (s << 2) + q;
      const int l = ((ch & 15) << 2) + (ch >> 5);
      const int n0 = ((ch >> 4) & 1) << 3;
      const float* wp = w + l * 1024 + m * 16 + n0;
      ob = __builtin_amdgcn_mfma_f32_16x16x32_bf16(__builtin_bit_cast(bf16x8, ar),
                                                   mk_bw(wp), ob, 0, 0, 0);
    }
  }

  #pragma unroll
  for (int r = 0; r < 4; ++r)
    out[((size_t)(wg0 + (q << 2) + r) << 6) + m] = ob[r];
}

extern "C" void kernel_launch(void* const* d_in, const int* in_sizes, int n_in,
                              void* d_out, int out_size, void* d_ws, size_t ws_size,
                              hipStream_t stream) {
  const float* nodes = (const float*)d_in[0];
  const int*   nlist = (const int*)d_in[1];
  const float* edges = (const float*)d_in[2];
  const float* w     = (const float*)d_in[3];
  float* out = (float*)d_out;

  const size_t WT_BYTES = 131072;               // 64x1024 bf16
  const size_t NB_BYTES = (size_t)1 << 22;      // 2x16384x64 bf16 = 4 MB

  if (ws_size >= WT_BYTES + NB_BYTES) {
    unsigned short* wt = (unsigned short*)d_ws;
    unsigned short* nb = wt + 65536;
    prep_wt<<<256, 256, 0, stream>>>(w, wt);
    prep_nb<<<1024, 256, 0, stream>>>(nodes, nb);
    mp_fused<<<512, 256, 0, stream>>>(nlist, edges, wt, nb, out);
  } else if (ws_size >= WT_BYTES) {
    unsigned short* wt = (unsigned short*)d_ws;
    prep_wt<<<256, 256, 0, stream>>>(w, wt);
    mp_kernel<1><<<2048, 256, 0, stream>>>(nodes, nlist, edges, wt, w, out);
  } else {
    mp_kernel<0><<<2048, 256, 0, stream>>>(nodes, nlist, edges, nullptr, w, out);
  }
}